// Round 4
// baseline (162.704 us; speedup 1.0000x reference)
//
#include <hip/hip_runtime.h>
#include <math.h>

typedef __attribute__((ext_vector_type(8))) short bf16x8;
typedef __attribute__((ext_vector_type(4))) float f32x4;

#define PI_F 3.14159265358979323846f

__device__ __forceinline__ unsigned short f2bf(float f) {
  unsigned int u = __float_as_uint(f);
  u += 0x7FFFu + ((u >> 16) & 1u);   // RNE to bf16
  return (unsigned short)(u >> 16);
}

__device__ __forceinline__ void async_ld16(const unsigned short* g, unsigned short* l) {
  __builtin_amdgcn_global_load_lds(
      (const __attribute__((address_space(1))) void*)g,
      (__attribute__((address_space(3))) void*)l,
      16, 0, 0);
}

// fast erf, A&S 7.1.26, |err| <= 1.5e-7 absolute
__device__ __forceinline__ float fast_erf(float x) {
  float a = fabsf(x);
  float t = 1.0f / fmaf(0.3275911f, a, 1.0f);
  float p = t * fmaf(t, fmaf(t, fmaf(t, fmaf(t, 1.061405429f, -1.453152027f),
                                     1.421413741f), -0.284496736f), 0.254829592f);
  float e = __expf(-a * a);
  float r = 1.0f - p * e;
  return copysignf(r, x);
}

__device__ __forceinline__ float fast_tanh(float a) {
  float e = __expf(2.0f * a);
  return 1.0f - 2.0f / (e + 1.0f);
}

// ---------------- fp32 -> bf16 convert (adj + Wg) + gate cos/sin precompute ----
__global__ __launch_bounds__(256)
void cvt_bf16_kernel(const float* __restrict__ s0, unsigned short* __restrict__ d0, int n40,
                     const float* __restrict__ s1, unsigned short* __restrict__ d1, int n41,
                     const float* __restrict__ qw, float* __restrict__ gcs) {
  int gi = blockIdx.x * 256 + threadIdx.x;
  if (gi < n40) {
    float4 v = ((const float4*)s0)[gi];
    ushort4 o; o.x = f2bf(v.x); o.y = f2bf(v.y); o.z = f2bf(v.z); o.w = f2bf(v.w);
    ((ushort4*)d0)[gi] = o;
  } else if (gi < n40 + n41) {
    int i = gi - n40;
    float4 v = ((const float4*)s1)[i];
    ushort4 o; o.x = f2bf(v.x); o.y = f2bf(v.y); o.z = f2bf(v.z); o.w = f2bf(v.w);
    ((ushort4*)d1)[i] = o;
  } else {
    int w = gi - (n40 + n41);
    if (w < 16) {
      float hh = 0.5f * qw[w];
      gcs[w] = cosf(hh);
      gcs[16 + w] = sinf(hh);
    }
  }
}

// ---------------- transpose + convert: x (16,1024,256) -> xT (16,256,1024) bf16 ----------------
__global__ __launch_bounds__(256)
void transpose_cvt_kernel(const float* __restrict__ x, unsigned short* __restrict__ xT) {
  __shared__ float tile[32][33];
  int jt = blockIdx.x;   // 0..31
  int ht = blockIdx.y;   // 0..7
  int b  = blockIdx.z;   // 0..15
  int tx = threadIdx.x;  // 0..31
  int ty = threadIdx.y;  // 0..7
  const float* xb = x + (size_t)b * 1024 * 256;
  #pragma unroll
  for (int i = 0; i < 4; i++) {
    int j = jt * 32 + ty + i * 8;
    tile[ty + i * 8][tx] = xb[(size_t)j * 256 + ht * 32 + tx];
  }
  __syncthreads();
  unsigned short* xTb = xT + (size_t)b * 256 * 1024;
  #pragma unroll
  for (int i = 0; i < 4; i++) {
    int h = ht * 32 + ty + i * 8;
    xTb[(size_t)h * 1024 + jt * 32 + tx] = f2bf(tile[tx][ty + i * 8]);
  }
}

// ---------------- MFMA GEMM, C = A * Bt^T, tile 128(M) x 64(N) x 32(K) ----
// MODE 0: store bf16 C.  MODE 1: bias + GELU(erf), store fp32 C.
template<int MODE>
__global__ __launch_bounds__(256)
void gemm_bt_kernel(const unsigned short* __restrict__ A,
                    const unsigned short* __restrict__ Bt,
                    void* __restrict__ C,
                    const float* __restrict__ bias,
                    int K, int tilesM, int tilesN,
                    long long strideA, long long strideBt, long long strideC, int ldC) {
  __shared__ unsigned short As[128 * 32];
  __shared__ unsigned short Bs[64 * 32];
  int tiles = tilesM * tilesN;
  int b   = blockIdx.x / tiles;
  int rr  = blockIdx.x % tiles;
  int im  = rr / tilesN;
  int in_ = rr % tilesN;
  const unsigned short* Ab  = A  + (long long)b * strideA  + (long long)im * 128 * K;
  const unsigned short* Btb = Bt + (long long)b * strideBt + (long long)in_ * 64 * K;

  int t = threadIdx.x;
  int wv = t >> 6, lane = t & 63;
  int wm = wv >> 1, wn = wv & 1;
  int l15 = lane & 15, quad = lane >> 4;
  int row0 = t >> 2, cg = t & 3;

  f32x4 acc[4][2] = {};

  for (int kk = 0; kk < K; kk += 32) {
    __syncthreads();
    #pragma unroll
    for (int q = 0; q < 2; q++) {
      int row = row0 + q * 64;
      async_ld16(Ab + (long long)row * K + kk + cg * 8,
                 &As[(wv * 16 + q * 64) * 32]);
    }
    async_ld16(Btb + (long long)row0 * K + kk + cg * 8,
               &Bs[wv * 16 * 32]);
    __syncthreads();
    bf16x8 af[4], bfr[2];
    #pragma unroll
    for (int mt = 0; mt < 4; mt++)
      af[mt] = *(const bf16x8*)&As[(wm * 64 + mt * 16 + l15) * 32 + quad * 8];
    #pragma unroll
    for (int nt = 0; nt < 2; nt++)
      bfr[nt] = *(const bf16x8*)&Bs[(wn * 32 + nt * 16 + l15) * 32 + quad * 8];
    #pragma unroll
    for (int mt = 0; mt < 4; mt++)
      #pragma unroll
      for (int nt = 0; nt < 2; nt++)
        acc[mt][nt] = __builtin_amdgcn_mfma_f32_16x16x32_bf16(af[mt], bfr[nt], acc[mt][nt], 0, 0, 0);
  }

  unsigned short* Cb_bf = (unsigned short*)C + (long long)b * strideC;
  float*          Cb_f  = (float*)C          + (long long)b * strideC;
  int n0 = in_ * 64;
  #pragma unroll
  for (int mt = 0; mt < 4; mt++) {
    #pragma unroll
    for (int nt = 0; nt < 2; nt++) {
      int colg = n0 + wn * 32 + nt * 16 + l15;
      #pragma unroll
      for (int r = 0; r < 4; r++) {
        long long rowg = (long long)im * 128 + wm * 64 + mt * 16 + quad * 4 + r;
        float v = acc[mt][nt][r];
        if (MODE == 0) {
          Cb_bf[rowg * ldC + colg] = f2bf(v);
        } else {
          v += bias[colg];
          v = 0.5f * v * (1.0f + fast_erf(v * 0.7071067811865475f));
          Cb_f[rowg * ldC + colg] = v;
        }
      }
    }
  }
}

// ---------------- 8-qubit entangler gates (shared by U-builder) ----------------
// stored amp index s: bits 0..5 = lane L, bits 6..7 = register r.
// CNOT rings DEFERRED (linear maps R on index bits):
//   layer-2 RX pair masks = R^-1 e_w = {03,06,0C,18,30,60,C0,83}
//   stored->logical map: n = R^2 s, rows of R^2 = {AB,FD,FA,F5,EA,D5,AA,55}
template<int ML, int MR>
__device__ __forceinline__ void apply_rx(float re[4], float im[4], float c, float s) {
  float pr[4], pi[4];
  #pragma unroll
  for (int r = 0; r < 4; r++) {
    float vr = re[r ^ MR], vi = im[r ^ MR];
    if (ML) { vr = __shfl_xor(vr, ML, 64); vi = __shfl_xor(vi, ML, 64); }
    pr[r] = vr; pi[r] = vi;
  }
  #pragma unroll
  for (int r = 0; r < 4; r++) {
    re[r] = fmaf(c, re[r],  s * pi[r]);
    im[r] = fmaf(c, im[r], -s * pr[r]);
  }
}

// ---------------- U-builder: simulate entangler on 256 basis vectors ----------------
// wave wv of block handles basis k = blockIdx*4+wv. Output Bt[512][256] bf16:
// rows 0..255 = Ure[n][k], rows 256..511 = Uim[n][k]  (k contiguous).
__global__ __launch_bounds__(256)
void u_builder_kernel(const float* __restrict__ gcs, unsigned short* __restrict__ Uri) {
  int t = threadIdx.x;
  int wv = t >> 6, L = t & 63;
  int k = blockIdx.x * 4 + wv;

  float re[4], im[4];
  #pragma unroll
  for (int r = 0; r < 4; r++) { re[r] = (r * 64 + L == k) ? 1.f : 0.f; im[r] = 0.f; }

  // layer 1 RX (F = I)
  apply_rx<1, 0>(re, im, gcs[0], gcs[16]);
  apply_rx<2, 0>(re, im, gcs[1], gcs[17]);
  apply_rx<4, 0>(re, im, gcs[2], gcs[18]);
  apply_rx<8, 0>(re, im, gcs[3], gcs[19]);
  apply_rx<16, 0>(re, im, gcs[4], gcs[20]);
  apply_rx<32, 0>(re, im, gcs[5], gcs[21]);
  apply_rx<0, 1>(re, im, gcs[6], gcs[22]);
  apply_rx<0, 2>(re, im, gcs[7], gcs[23]);
  // layer 2 RX (F = R)
  apply_rx<3, 0>(re, im, gcs[8], gcs[24]);
  apply_rx<6, 0>(re, im, gcs[9], gcs[25]);
  apply_rx<12, 0>(re, im, gcs[10], gcs[26]);
  apply_rx<24, 0>(re, im, gcs[11], gcs[27]);
  apply_rx<48, 0>(re, im, gcs[12], gcs[28]);
  apply_rx<32, 1>(re, im, gcs[13], gcs[29]);
  apply_rx<0, 3>(re, im, gcs[14], gcs[30]);
  apply_rx<3, 2>(re, im, gcs[15], gcs[31]);

  const int M[8] = {0xAB, 0xFD, 0xFA, 0xF5, 0xEA, 0xD5, 0xAA, 0x55};
  #pragma unroll
  for (int r = 0; r < 4; r++) {
    int n = 0;
    #pragma unroll
    for (int w = 0; w < 8; w++) {
      int bit = (__popc(L & (M[w] & 63)) ^ __popc((r << 6) & M[w])) & 1;
      n |= bit << w;
    }
    Uri[(size_t)n * 256 + k] = f2bf(re[r]);
    Uri[(size_t)(256 + n) * 256 + k] = f2bf(im[r]);
  }
}

// fold-reduce 8 values across 64 lanes: 10 shuffles. On exit v[0] of lane L holds
// the wave-sum of value w(L) = 4*(L&1) + (L&2) + ((L>>2)&1).
__device__ __forceinline__ void fold_reduce8(float v[8], int L) {
  #pragma unroll
  for (int step = 0; step < 3; step++) {
    int d = 1 << step;
    int half = 4 >> step;
    bool hi = (L & d) != 0;
    #pragma unroll
    for (int w = 0; w < half; w++) {
      float send = hi ? v[w] : v[w + half];
      float recv = __shfl_xor(send, d, 64);
      v[w] = (hi ? v[w + half] : v[w]) + recv;
    }
  }
  v[0] += __shfl_xor(v[0], 8, 64);
  v[0] += __shfl_xor(v[0], 16, 64);
  v[0] += __shfl_xor(v[0], 32, 64);
}

// ---------------- P0-builder: angles -> RY product state (bf16, logical basis) ----
// one sample per wave; lane L writes entries n = 4L..4L+3 (n bit w <-> wire w).
__global__ __launch_bounds__(256)
void p0_builder_kernel(const float* __restrict__ g,
                       const float* __restrict__ Wpre, const float* __restrict__ bpre,
                       unsigned short* __restrict__ P0) {
  __shared__ float sWpre[2048];   // [w][h]  8x256
  int t = threadIdx.x;
  for (int i = t; i < 2048; i += 256) sWpre[i] = Wpre[i];
  __syncthreads();

  int wv = t >> 6, L = t & 63;
  long long s = (long long)blockIdx.x * 4 + wv;
  float4 gq = ((const float4*)(g + s * 256))[L];

  float ang[8];
  #pragma unroll
  for (int w = 0; w < 8; w++) {
    float4 wp = *(const float4*)&sWpre[w * 256 + 4 * L];
    float a = gq.x * wp.x;
    a = fmaf(gq.y, wp.y, a);
    a = fmaf(gq.z, wp.z, a);
    a = fmaf(gq.w, wp.w, a);
    ang[w] = a;
  }
  fold_reduce8(ang, L);
  float angf[8];
  #pragma unroll
  for (int w = 0; w < 8; w++) {
    int src = ((w >> 2) & 1) | ((w & 2)) | ((w & 1) << 2);
    angf[w] = __shfl(ang[0], src, 64);
  }

  float cw[8], sw[8];
  #pragma unroll
  for (int w = 0; w < 8; w++) {
    float th = (0.5f * PI_F) * fast_tanh(angf[w] + bpre[w]);
    cw[w] = __cosf(th); sw[w] = __sinf(th);
  }

  float pl = 1.f;
  #pragma unroll
  for (int b = 0; b < 6; b++) pl *= ((L >> b) & 1) ? sw[b + 2] : cw[b + 2];

  ushort4 o;
  o.x = f2bf(pl * cw[0] * cw[1]);
  o.y = f2bf(pl * sw[0] * cw[1]);
  o.z = f2bf(pl * cw[0] * sw[1]);
  o.w = f2bf(pl * sw[0] * sw[1]);
  ((ushort4*)(P0 + s * 256))[L] = o;
}

// ---------------- qgemm: S = P0 x Uri^T (M-tile 32, N = 512 full) + fused measurement
// + Wpost projection. Each block owns 32 complete sample rows.
__global__ __launch_bounds__(256)
void qgemm_kernel(const unsigned short* __restrict__ P0,
                  const unsigned short* __restrict__ Uri,
                  const float* __restrict__ Wpost, const float* __restrict__ bpost,
                  float* __restrict__ out) {
  __shared__ unsigned short As[32 * 32];     // 2 KB
  __shared__ unsigned short Bs[512 * 32];    // 32 KB
  __shared__ float sWpostT[2048];            // 8 KB, [w][h]
  __shared__ float sBpost[256];              // 1 KB
  __shared__ float zpart[4 * 32 * 8];        // 4 KB, [wv][row][w]
  __shared__ float zfin[32 * 8];             // 1 KB, [row][w]

  int t = threadIdx.x;
  int wv = t >> 6, lane = t & 63;
  int l15 = lane & 15, quad = lane >> 4;

  for (int i = t; i < 2048; i += 256) sWpostT[i] = Wpost[(i & 255) * 8 + (i >> 8)];
  sBpost[t] = bpost[t];

  const unsigned short* Ab = P0 + (size_t)blockIdx.x * 32 * 256;

  f32x4 acc[2][8] = {};

  for (int kk = 0; kk < 256; kk += 32) {
    __syncthreads();
    // A: 32 rows x 32 k = 128 chunks, waves 0-1
    if (wv < 2) {
      int gch = wv * 64 + lane;
      int m = gch >> 2, cg = gch & 3;
      async_ld16(Ab + m * 256 + kk + cg * 8, &As[(wv * 64) * 8]);
    }
    // B: 512 rows x 32 k = 2048 chunks, 8 rounds of 256
    #pragma unroll
    for (int rd = 0; rd < 8; rd++) {
      int gch = rd * 256 + t;
      int c = gch >> 2, cg = gch & 3;
      async_ld16(Uri + (size_t)c * 256 + kk + cg * 8, &Bs[(rd * 256 + wv * 64) * 8]);
    }
    __syncthreads();
    bf16x8 af[2], bfr[8];
    #pragma unroll
    for (int mt = 0; mt < 2; mt++)
      af[mt] = *(const bf16x8*)&As[(mt * 16 + l15) * 32 + quad * 8];
    #pragma unroll
    for (int nt = 0; nt < 8; nt++)
      bfr[nt] = *(const bf16x8*)&Bs[(wv * 128 + nt * 16 + l15) * 32 + quad * 8];
    #pragma unroll
    for (int mt = 0; mt < 2; mt++)
      #pragma unroll
      for (int nt = 0; nt < 8; nt++)
        acc[mt][nt] = __builtin_amdgcn_mfma_f32_16x16x32_bf16(af[mt], bfr[nt], acc[mt][nt], 0, 0, 0);
  }

  // ---- fused measurement: z_w[row] = sum_c (-1)^{n(c)_w} acc_c^2 ----
  // col c = wv*128 + nt*16 + l15 ; n = c & 255 ; n bits: 0..3 = l15, 4..6 = nt, 7 = wv&1
  float wsgn = (wv & 1) ? -1.f : 1.f;
  #pragma unroll
  for (int mt = 0; mt < 2; mt++) {
    #pragma unroll
    for (int r = 0; r < 4; r++) {
      float v[8];
      #pragma unroll
      for (int nt = 0; nt < 8; nt++) { float a = acc[mt][nt][r]; v[nt] = a * a; }
      float s0p = v[0] + v[1], s0m = v[0] - v[1];
      float s1p = v[2] + v[3], s1m = v[2] - v[3];
      float s2p = v[4] + v[5], s2m = v[4] - v[5];
      float s3p = v[6] + v[7], s3m = v[6] - v[7];
      float h0 = (s0p + s1p) + (s2p + s3p);
      float h1 = (s0m + s1m) + (s2m + s3m);   // sign on n bit4
      float h2 = (s0p - s1p) + (s2p - s3p);   // sign on n bit5
      float h4 = (s0p + s1p) - (s2p + s3p);   // sign on n bit6
      float P[8];
      P[0] = (l15 & 1) ? -h0 : h0;
      P[1] = (l15 & 2) ? -h0 : h0;
      P[2] = (l15 & 4) ? -h0 : h0;
      P[3] = (l15 & 8) ? -h0 : h0;
      P[4] = h1; P[5] = h2; P[6] = h4;
      P[7] = wsgn * h0;
      // fold over l15 bits 0..2 (value fold), then bit 3 (plain add)
      #pragma unroll
      for (int step = 0; step < 3; step++) {
        int d = 1 << step;
        int half = 4 >> step;
        bool hi = (lane & d) != 0;
        #pragma unroll
        for (int w = 0; w < half; w++) {
          float send = hi ? P[w] : P[w + half];
          float recv = __shfl_xor(send, d, 64);
          P[w] = (hi ? P[w + half] : P[w]) + recv;
        }
      }
      P[0] += __shfl_xor(P[0], 8, 64);
      int row = mt * 16 + quad * 4 + r;
      int widx = 4 * (l15 & 1) + 2 * ((l15 >> 1) & 1) + ((l15 >> 2) & 1);
      if (l15 < 8) zpart[wv * 256 + row * 8 + widx] = P[0];
    }
  }
  __syncthreads();
  zfin[t] = zpart[t] + zpart[256 + t] + zpart[512 + t] + zpart[768 + t];
  __syncthreads();

  // ---- projection: wave wv handles rows 8wv..8wv+7; lane L covers cols 4L..4L+3 ----
  float4 wp[8];
  #pragma unroll
  for (int w = 0; w < 8; w++) wp[w] = *(const float4*)&sWpostT[w * 256 + 4 * lane];
  float4 bp = *(const float4*)&sBpost[4 * lane];
  #pragma unroll
  for (int rr = 0; rr < 8; rr++) {
    int row = wv * 8 + rr;
    float4 z0 = *(const float4*)&zfin[row * 8];
    float4 z1 = *(const float4*)&zfin[row * 8 + 4];
    float4 v = bp;
    v.x = fmaf(z0.x, wp[0].x, v.x); v.y = fmaf(z0.x, wp[0].y, v.y);
    v.z = fmaf(z0.x, wp[0].z, v.z); v.w = fmaf(z0.x, wp[0].w, v.w);
    v.x = fmaf(z0.y, wp[1].x, v.x); v.y = fmaf(z0.y, wp[1].y, v.y);
    v.z = fmaf(z0.y, wp[1].z, v.z); v.w = fmaf(z0.y, wp[1].w, v.w);
    v.x = fmaf(z0.z, wp[2].x, v.x); v.y = fmaf(z0.z, wp[2].y, v.y);
    v.z = fmaf(z0.z, wp[2].z, v.z); v.w = fmaf(z0.z, wp[2].w, v.w);
    v.x = fmaf(z0.w, wp[3].x, v.x); v.y = fmaf(z0.w, wp[3].y, v.y);
    v.z = fmaf(z0.w, wp[3].z, v.z); v.w = fmaf(z0.w, wp[3].w, v.w);
    v.x = fmaf(z1.x, wp[4].x, v.x); v.y = fmaf(z1.x, wp[4].y, v.y);
    v.z = fmaf(z1.x, wp[4].z, v.z); v.w = fmaf(z1.x, wp[4].w, v.w);
    v.x = fmaf(z1.y, wp[5].x, v.x); v.y = fmaf(z1.y, wp[5].y, v.y);
    v.z = fmaf(z1.y, wp[5].z, v.z); v.w = fmaf(z1.y, wp[5].w, v.w);
    v.x = fmaf(z1.z, wp[6].x, v.x); v.y = fmaf(z1.z, wp[6].y, v.y);
    v.z = fmaf(z1.z, wp[6].z, v.z); v.w = fmaf(z1.z, wp[6].w, v.w);
    v.x = fmaf(z1.w, wp[7].x, v.x); v.y = fmaf(z1.w, wp[7].y, v.y);
    v.z = fmaf(z1.w, wp[7].z, v.z); v.w = fmaf(z1.w, wp[7].w, v.w);
    ((float4*)(out + ((size_t)blockIdx.x * 32 + row) * 256))[lane] = v;
  }
}

// ---------------- host launch ----------------
extern "C" void kernel_launch(void* const* d_in, const int* in_sizes, int n_in,
                              void* d_out, int out_size, void* d_ws, size_t ws_size,
                              hipStream_t stream) {
  const float* x     = (const float*)d_in[0];  // (16,1024,256)
  const float* adj   = (const float*)d_in[1];  // (1024,1024)
  const float* Wg    = (const float*)d_in[2];  // (256,256)
  const float* bg    = (const float*)d_in[3];  // (256,)
  const float* Wpre  = (const float*)d_in[4];  // (8,256)
  const float* bpre  = (const float*)d_in[5];  // (8,)
  const float* qw    = (const float*)d_in[6];  // (2,8)
  const float* Wpost = (const float*)d_in[7];  // (256,8)
  const float* bpost = (const float*)d_in[8];  // (256,)
  float* out = (float*)d_out;                  // (16,1024,256)

  char* ws = (char*)d_ws;
  unsigned short* adj_bf  = (unsigned short*)(ws + 0);          // 2 MiB
  unsigned short* Wg_bf   = (unsigned short*)(ws + 2097152);    // 128 KiB
  unsigned short* xagg_bf = (unsigned short*)(ws + 2228224);    // 8 MiB  (16384 x 256)
  unsigned short* xT_bf   = (unsigned short*)(ws + 10616832);   // 8 MiB  (16 x 256 x 1024)
  float*          gbuf    = (float*)(ws + 19005440);            // 16 MiB (16384 x 256)
  float*          gcs     = (float*)(ws + 35782656);            // 128 B
  unsigned short* Uri     = (unsigned short*)(ws + 35782784);   // 256 KiB (512 x 256)
  unsigned short* P0      = (unsigned short*)(ws + 36044928);   // 8 MiB  (16384 x 256)

  // 1) converts (adj + Wg + gate table) and x transpose
  cvt_bf16_kernel<<<1089, 256, 0, stream>>>(adj, adj_bf, 1024 * 1024 / 4,
                                            Wg, Wg_bf, 256 * 256 / 4, qw, gcs);
  transpose_cvt_kernel<<<dim3(32, 8, 16), dim3(32, 8), 0, stream>>>(x, xT_bf);

  // 2) circuit unitary from gate table (256 basis sims)
  u_builder_kernel<<<64, 256, 0, stream>>>(gcs, Uri);

  // 3) x_agg[b] = adj @ x[b]  -> bf16
  gemm_bt_kernel<0><<<512, 256, 0, stream>>>(adj_bf, xT_bf, (void*)xagg_bf, nullptr,
                                             1024, 8, 4,
                                             0LL, 262144LL, 262144LL, 256);

  // 4) g = gelu(x_agg @ Wg^T + bg) -> fp32
  gemm_bt_kernel<1><<<512, 256, 0, stream>>>(xagg_bf, Wg_bf, (void*)gbuf, bg,
                                             256, 128, 4,
                                             0LL, 0LL, 0LL, 256);

  // 5) P0 = RY product state per sample (bf16)
  p0_builder_kernel<<<4096, 256, 0, stream>>>(gbuf, Wpre, bpre, P0);

  // 6) S = P0 x Uri^T + fused measurement + Wpost projection
  qgemm_kernel<<<512, 256, 0, stream>>>(P0, Uri, Wpost, bpost, out);
}